// Round 12
// baseline (294.425 us; speedup 1.0000x reference)
//
#include <hip/hip_runtime.h>

typedef float    f32x4 __attribute__((ext_vector_type(4)));
typedef _Float16 f16x8 __attribute__((ext_vector_type(8)));
typedef _Float16 f16x4 __attribute__((ext_vector_type(4)));

// async global->LDS, 16B per lane (dest = wave-uniform base + lane*16)
__device__ __forceinline__ void gload16(const void* g, void* l) {
  __builtin_amdgcn_global_load_lds(
      (__attribute__((address_space(1))) void*)(const void*)g,
      (__attribute__((address_space(3))) void*)l,
      16, 0, 0);
}

// ================== 128x256 BT-GEMM engine, 2 blocks/CU ==================
// D = A(MxK) * B(NxK)^T, f16 in, f32 acc. 512 threads = 8 waves (2M x 4N),
// per-wave 64x64 = acc[4][4]. BK=32, 3 LDS bufs (72KB static), stage 2
// ahead, one barrier + counted vmcnt(3)/K-tile (never drains mid-loop).
// XOR swizzle on source + ds_read.
// EPI 0: out1(f16) = acc + bias[col]                        [kq proj, FFN1]
// EPI 3: out0(f32) = (f32)residh + relu(acc)                [final]
// EPI 4: E' = exp(acc - m_chunk) -> out1(f16); (m,Z) partials -> out0,out2
// EPI 6: fused PV: A-frag *= cv (global c-table via compiler-tracked
//        1-ahead register prefetch); out1(f16) = acc + resid(f32)
template <int EPI>
__global__ __launch_bounds__(512, 4) void gemm_kt(
    const _Float16* __restrict__ A, size_t sA, int lda,
    const _Float16* __restrict__ B, size_t sB, int ldb,
    float* __restrict__ out0, _Float16* __restrict__ out1,
    float* __restrict__ out2,
    size_t sO, int ldo,
    const float* __restrict__ bias,
    const float* __restrict__ resid,
    const _Float16* __restrict__ residh,
    const _Float16* __restrict__ cf,
    int K) {
  __shared__ _Float16 lds[3 * 12288];  // 73728 B -> 2 blocks/CU for all EPIs

  // XCD-bijective swizzle (all grids are multiples of 8 blocks)
  const int gx = gridDim.x, gy = gridDim.y;
  const int nblk = gx * gy * gridDim.z;
  int lin = (blockIdx.z * gy + blockIdx.y) * gx + blockIdx.x;
  lin = (lin & 7) * (nblk >> 3) + (lin >> 3);
  const int b  = lin / (gx * gy);
  const int r2 = lin - b * gx * gy;
  const int m0 = (r2 / gx) * 128;
  const int n0 = (r2 - (r2 / gx) * gx) * 256;

  const int t = threadIdx.x, lane = t & 63, w = t >> 6;
  const int wr = w >> 2;          // wave M-half: rows m0+wr*64..+63
  const int wc = w & 3;           // wave N-quarter: cols n0+wc*64..+63
  const int lr = lane & 15, lq = lane >> 4;

  const _Float16* Ab = A + (size_t)b * sA;
  const _Float16* Bb = B + (size_t)b * sB;

  // staging: thread t stages A seg t, B segs t and t+512 (16B each)
  const int arow = t >> 2;
  const int acol = ((t & 3) ^ ((arow >> 1) & 3)) * 8;  // pre-swizzled source col
  const _Float16* a_src  = Ab + (size_t)(m0 + arow) * lda + acol;
  const _Float16* b_src0 = Bb + (size_t)(n0 + arow) * ldb + acol;
  const _Float16* b_src1 = b_src0 + (size_t)128 * ldb;  // +128 rows: same swizzle class
  const int a_dst  = t * 8;
  const int b_dst0 = 4096 + t * 8;
  const int b_dst1 = 4096 + (t + 512) * 8;

  // ds_read bases (swizzled)
  const int swz  = ((lr >> 1) & 3) << 3;
  const int koff = (lq * 8) ^ swz;                       // swizzled k slot in LDS
  const int a_rd = (wr * 64 + lr) * 32 + koff;           // + f*512
  const int b_rd = 4096 + (wc * 64 + lr) * 32 + koff;    // + j*512

  f32x4 acc[4][4];
#pragma unroll
  for (int f = 0; f < 4; ++f)
#pragma unroll
    for (int j = 0; j < 4; ++j) acc[f][j] = (f32x4){0.f, 0.f, 0.f, 0.f};

  const int NT = K >> 5;

  // ---- prologue ----
  // EPI6: cv pipeline base. Fragment's global k-group is lq (store/read XOR
  // cancels); c row is the wave's 64-row chunk (m0>>6)+wr. Plain C++ loads:
  // the compiler tracks completion (round-8/9's inline-asm pipeline did not).
  const _Float16* cvp = nullptr;
  f16x8 cvCur;
  if constexpr (EPI == 6) {
    cvp = cf + ((size_t)b * 32 + (m0 >> 6) + wr) * 2048 + lq * 8;
    cvCur = *(const f16x8*)cvp;  // kt = 0
  }
  gload16(a_src,       lds + a_dst);
  gload16(b_src0,      lds + b_dst0);
  gload16(b_src1,      lds + b_dst1);
  gload16(a_src  + 32, lds + 12288 + a_dst);
  gload16(b_src0 + 32, lds + 12288 + b_dst0);
  gload16(b_src1 + 32, lds + 12288 + b_dst1);

  int buf = 0;
  for (int kt = 0; kt < NT; ++kt) {
    // counted wait: in-order vmcnt retirement means vmcnt(3) retires
    // everything older than the newest 3 ops — tile kt's stages are
    // guaranteed landed; tile kt+1's stages (mostly) stay in flight
    if (kt + 1 < NT) asm volatile("s_waitcnt vmcnt(3)" ::: "memory");
    else             asm volatile("s_waitcnt vmcnt(0)" ::: "memory");
    __builtin_amdgcn_s_barrier();
    __builtin_amdgcn_sched_barrier(0);  // no ds_read hoists above the barrier

    const _Float16* lb = lds + buf * 12288;
    const int nb = (buf + 2 >= 3) ? buf - 1 : buf + 2;
    _Float16* ln = lds + nb * 12288;

    f16x8 af[4], bf[4];
#pragma unroll
    for (int f = 0; f < 4; ++f) {
      af[f] = *(const f16x8*)(lb + a_rd + f * 512);
      if constexpr (EPI == 6) af[f] = af[f] * cvCur;
    }
#pragma unroll
    for (int j = 0; j < 4; ++j) bf[j] = *(const f16x8*)(lb + b_rd + j * 512);

    f16x8 cvNext;
    if constexpr (EPI == 6) {
      const int kn = (kt + 1 < NT) ? (kt + 1) * 32 : 0;  // branchless guard
      cvNext = *(const f16x8*)(cvp + kn);
    }
    if (kt + 2 < NT) {
      const int ko = (kt + 2) * 32;
      gload16(a_src  + ko, ln + a_dst);
      gload16(b_src0 + ko, ln + b_dst0);
      gload16(b_src1 + ko, ln + b_dst1);
    }
    __builtin_amdgcn_s_setprio(1);
#pragma unroll
    for (int f = 0; f < 4; ++f)
#pragma unroll
      for (int j = 0; j < 4; ++j)
        acc[f][j] = __builtin_amdgcn_mfma_f32_16x16x32_f16(af[f], bf[j], acc[f][j], 0, 0, 0);
    __builtin_amdgcn_s_setprio(0);
    if constexpr (EPI == 6) cvCur = cvNext;
    __builtin_amdgcn_sched_barrier(0);  // nothing sinks into next tile
    buf = (buf + 1 >= 3) ? 0 : buf + 1;
  }

  // ---- epilogues. D frag: col = lr, row = lq*4 + r ----
  if constexpr (EPI == 4) {
#pragma unroll
    for (int j = 0; j < 4; ++j) {
      float m = -3.4e38f;
#pragma unroll
      for (int f = 0; f < 4; ++f)
#pragma unroll
        for (int r = 0; r < 4; ++r) m = fmaxf(m, acc[f][j][r]);
#pragma unroll
      for (int d = 16; d <= 32; d <<= 1) m = fmaxf(m, __shfl_xor(m, d, 64));
      // E' = exp(acc - m_chunk), store f16; Z from rounded values
      float Z = 0.f;
      const int col = n0 + wc * 64 + j * 16 + lr;
#pragma unroll
      for (int f = 0; f < 4; ++f)
#pragma unroll
        for (int r = 0; r < 4; ++r) {
          const _Float16 eh = (_Float16)__expf(acc[f][j][r] - m);
          const int row = m0 + wr * 64 + f * 16 + lq * 4 + r;
          out1[(size_t)b * sO + (size_t)row * ldo + col] = eh;
          Z += (float)eh;
        }
#pragma unroll
      for (int d = 16; d <= 32; d <<= 1) Z += __shfl_xor(Z, d, 64);
      if (lq == 0) {
        const int chunk = (m0 >> 6) + wr;  // 32 chunks of 64 rows per batch
        const size_t sidx = ((size_t)b * 32 + chunk) * 2048 + col;
        out0[sidx] = m;
        out2[sidx] = Z;
      }
    }
  } else {
#pragma unroll
    for (int f = 0; f < 4; ++f)
#pragma unroll
      for (int j = 0; j < 4; ++j)
#pragma unroll
        for (int r = 0; r < 4; ++r) {
          const int row = m0 + wr * 64 + f * 16 + lq * 4 + r;
          const int col = n0 + wc * 64 + j * 16 + lr;
          const size_t oidx = (size_t)b * sO + (size_t)row * ldo + col;
          float v = acc[f][j][r];
          if constexpr (EPI == 0) {
            if (bias) v += bias[col];
            out1[oidx] = (_Float16)v;
          } else if constexpr (EPI == 6) {
            out1[oidx] = (_Float16)(v + resid[oidx]);  // p in f16 only
          } else {  // EPI == 3
            out0[oidx] = (float)residh[oidx] + (v > 0.f ? v : 0.f);
          }
        }
  }
}

// ---- fp32 -> fp16 convert, 8 elems/thread (weights) ----
__global__ __launch_bounds__(256) void convert_f32_f16(const float* __restrict__ in,
                                                       _Float16* __restrict__ out, long n8) {
  long i = (long)blockIdx.x * blockDim.x + threadIdx.x;
  if (i >= n8) return;
  f32x4 v0 = *(const f32x4*)(in + i * 8);
  f32x4 v1 = *(const f32x4*)(in + i * 8 + 4);
  f16x8 o;
  o[0] = (_Float16)v0[0]; o[1] = (_Float16)v0[1]; o[2] = (_Float16)v0[2]; o[3] = (_Float16)v0[3];
  o[4] = (_Float16)v1[0]; o[5] = (_Float16)v1[1]; o[6] = (_Float16)v1[2]; o[7] = (_Float16)v1[3];
  *(f16x8*)(out + i * 8) = o;
}

// ---- concat bk,bq -> bkq[1536] ----
__global__ void concat_bias(const float* __restrict__ bk, const float* __restrict__ bq,
                            float* __restrict__ bkq) {
  const int i = blockIdx.x * 256 + threadIdx.x;
  if (i < 768) bkq[i] = bk[i];
  else if (i < 1536) bkq[i] = bq[i - 768];
}

// ---- combine 32 chunk partials per column -> c[b][chunk][col] (f16) ----
// c = exp(m_chunk - m) / Z
__global__ __launch_bounds__(256) void col_final(const float* __restrict__ pm,
                                                 const float* __restrict__ pZ,
                                                 _Float16* __restrict__ c) {
  const int b = blockIdx.z;
  const int col = blockIdx.x * 256 + threadIdx.x;
  float mv[32];
  float m = -3.4e38f;
#pragma unroll
  for (int k = 0; k < 32; ++k) {
    mv[k] = pm[((size_t)b * 32 + k) * 2048 + col];
    m = fmaxf(m, mv[k]);
  }
  float Z = 0.f;
#pragma unroll
  for (int k = 0; k < 32; ++k)
    Z += pZ[((size_t)b * 32 + k) * 2048 + col] * __expf(mv[k] - m);
  const float rZ = 1.f / Z;
#pragma unroll
  for (int k = 0; k < 32; ++k)
    c[((size_t)b * 32 + k) * 2048 + col] = (_Float16)(__expf(mv[k] - m) * rZ);
}

// ---- x[b][j][c] f32 -> xf[b][j][c] f16 AND xT[b][c][j] f16, one pass ----
__global__ void xprep(const float* __restrict__ x, _Float16* __restrict__ xf,
                      _Float16* __restrict__ xT) {
  __shared__ float tile[32][33];
  const int b = blockIdx.z;
  const int c0 = blockIdx.x * 32, j0 = blockIdx.y * 32;
  const float* xb = x + (size_t)b * 2048 * 768;
  const int tx = threadIdx.x, ty = threadIdx.y;  // 32 x 8
#pragma unroll
  for (int dy = 0; dy < 32; dy += 8)
    tile[ty + dy][tx] = xb[(size_t)(j0 + ty + dy) * 768 + c0 + tx];
  __syncthreads();
  // straight f16 copy, 4-wide vector stores
  {
    const int u = ty * 32 + tx;          // 0..255
    const int row = u >> 3, c4 = (u & 7) * 4;
    f16x4 o;
#pragma unroll
    for (int q = 0; q < 4; ++q) o[q] = (_Float16)tile[row][c4 + q];
    *(f16x4*)(xf + ((size_t)b * 2048 + j0 + row) * 768 + c0 + c4) = o;
  }
  // transposed f16
  _Float16* xTb = xT + (size_t)b * 768 * 2048;
#pragma unroll
  for (int dy = 0; dy < 32; dy += 8)
    xTb[(size_t)(c0 + ty + dy) * 2048 + j0 + tx] = (_Float16)tile[tx][ty + dy];
}

extern "C" void kernel_launch(void* const* d_in, const int* in_sizes, int n_in,
                              void* d_out, int out_size, void* d_ws, size_t ws_size,
                              hipStream_t stream) {
  const float* x  = (const float*)d_in[0];
  const float* Wk = (const float*)d_in[1];
  const float* bk = (const float*)d_in[2];
  const float* Wq = (const float*)d_in[3];
  const float* bq = (const float*)d_in[4];
  const float* W1 = (const float*)d_in[5];
  const float* W2 = (const float*)d_in[6];
  float* out = (float*)d_out;

  // ---- ws layout (~168 MiB peak) ----
  char* ws = (char*)d_ws;
  size_t off = 0;
  auto alloc = [&](size_t bytes) -> char* {
    char* p = ws + off;
    off += (bytes + 255) & ~(size_t)255;
    return p;
  };
  _Float16* xf = (_Float16*)alloc(25165824);   // x f16 row-major
  _Float16* kq = (_Float16*)alloc(50331648);   // [16384][1536] k|q; reused p_f16+c+h
  _Float16* Wf = (_Float16*)alloc(4718592);    // Wkq, W1, W2 f16
  _Float16* E  = (_Float16*)alloc(67108864);   // E' = exp(S - m_chunk) f16
  _Float16* xT = (_Float16*)alloc(25165824);   // x^T f16 [b][c][j]
  float*    pm = (float*)alloc(2097152);       // [8][32][2048] partial max
  float*    pZ = (float*)alloc(2097152);       // [8][32][2048] partial sumexp
  float*    bkq  = (float*)alloc(6144);

  _Float16* Wkqf = Wf;
  _Float16* W1f  = Wf + 2 * 589824;
  _Float16* W2f  = Wf + 3 * 589824;
  _Float16* pf16 = kq;                 // alias after E pass consumed kq
  _Float16* cT   = kq + 12582912;      // c table (1MiB) in dead kq space
  _Float16* hf16 = kq + 12582912;      // FFN1 out overwrites cT AFTER PV consumed
                                       // it (stream order); ends exactly at kq end

  const size_t sKQ = (size_t)2048 * 1536;
  const size_t sS  = (size_t)2048 * 2048;
  const size_t sKV = (size_t)2048 * 768;

  // 1. x prep (f16 + transpose in one pass over x) + weight converts
  xprep<<<dim3(24, 64, 8), dim3(32, 8), 0, stream>>>(x, xf, xT);
  convert_f32_f16<<<288, 256, 0, stream>>>(Wk, Wkqf, 73728);
  convert_f32_f16<<<288, 256, 0, stream>>>(Wq, Wkqf + 589824, 73728);
  convert_f32_f16<<<288, 256, 0, stream>>>(W1, W1f, 73728);
  convert_f32_f16<<<288, 256, 0, stream>>>(W2, W2f, 73728);
  concat_bias<<<6, 256, 0, stream>>>(bk, bq, bkq);

  // 2. merged projection: kq = x * Wkq^T + bkq  (M=16384, N=1536, K=768)
  gemm_kt<0><<<dim3(6, 128, 1), 512, 0, stream>>>(xf, 0, 768, Wkqf, 0, 768,
                                                  nullptr, kq, nullptr, 0, 1536,
                                                  bkq, nullptr, nullptr, nullptr, 768);

  // 3. E pass: S = k q^T; E' = exp(S - m_chunk) f16 + (m,Z) partials
  gemm_kt<4><<<dim3(8, 16, 8), 512, 0, stream>>>(kq, sKQ, 1536, kq + 768, sKQ, 1536,
                                                 pm, E, pZ, sS, 2048,
                                                 nullptr, nullptr, nullptr, nullptr, 768);
  col_final<<<dim3(8, 1, 8), 256, 0, stream>>>(pm, pZ, cT);

  // 4. fused PV: p = x + (E' .* c) x  (M=2048, N=768, K=2048), f16 out only
  gemm_kt<6><<<dim3(3, 16, 8), 512, 0, stream>>>(E, sS, 2048, xT, sKV, 2048,
                                                 nullptr, pf16, nullptr, sKV, 768,
                                                 nullptr, x, nullptr, cT, 2048);

  // 5. FFN1: h = p * W1^T (f16 out; overwrites cT — PV done)
  gemm_kt<0><<<dim3(3, 128, 1), 512, 0, stream>>>(pf16, 0, 768, W1f, 0, 768,
                                                  nullptr, hf16, nullptr, 0, 768,
                                                  nullptr, nullptr, nullptr, nullptr, 768);

  // 6. FFN2 + residual + relu: out = (f32)p_f16 + relu(h * W2^T)
  gemm_kt<3><<<dim3(3, 128, 1), 512, 0, stream>>>(hf16, 0, 768, W2f, 0, 768,
                                                  out, nullptr, nullptr, 0, 768,
                                                  nullptr, nullptr, pf16, nullptr, 768);
}

// Round 14
// 263.400 us; speedup vs baseline: 1.1178x; 1.1178x over previous
//
#include <hip/hip_runtime.h>

typedef float    f32x4 __attribute__((ext_vector_type(4)));
typedef _Float16 f16x8 __attribute__((ext_vector_type(8)));
typedef _Float16 f16x4 __attribute__((ext_vector_type(4)));

// async global->LDS, 16B per lane (dest = wave-uniform base + lane*16)
__device__ __forceinline__ void gload16(const void* g, void* l) {
  __builtin_amdgcn_global_load_lds(
      (__attribute__((address_space(1))) void*)(const void*)g,
      (__attribute__((address_space(3))) void*)l,
      16, 0, 0);
}

// coalesced f16 tile flush: LDS bounce region (8 wave regions x 4096 f16,
// row-major [64][64] with col XOR ((row&12)<<2)) -> global [128][256] tile.
// 8 iters x 512 threads x 8 f16 = 32768 = full 128x256 tile.
__device__ __forceinline__ void bounce_flush(const _Float16* lds, _Float16* gbase,
                                             int ldo, int t) {
#pragma unroll
  for (int it = 0; it < 8; ++it) {
    const int s = t + it * 512;
    const int R = s >> 5;            // tile row 0..127
    const int C = (s & 31) * 8;      // tile col 0..248
    const int wsrc = ((R >> 6) << 2) | (C >> 6);
    const f16x8 v = *(const f16x8*)(lds + wsrc * 4096 + (R & 63) * 64 +
                                    ((C & 63) ^ ((R & 12) << 2)));
    *(f16x8*)(gbase + (size_t)R * ldo + C) = v;
  }
}

// ================== 128x256 BT-GEMM engine ==================
// D = A(MxK) * B(NxK)^T, f16 in, f32 acc. 512 threads = 8 waves (2M x 4N),
// per-wave 64x64 = acc[4][4]. BK=32, 3 LDS bufs (72KB static), stage 2
// ahead, one barrier + counted vmcnt(3)/K-tile. XOR swizzle source+read.
// f16 epilogues (0,4,6) use the LDS-bounce coalesced store.
// EPI 0: out1(f16) = acc + bias[col]                        [kq proj, FFN1]
// EPI 3: out0(f32) = (f32)residh + relu(acc)                [final]
// EPI 4: E' = exp(acc - m_chunk) -> out1(f16); (m,Z) partials -> out0,out2
// EPI 6: fused PV: A-frag *= cv (LDS c-table); out1(f16) = acc + resid(f32)
template <int EPI>
__global__ __launch_bounds__(512, 4) void gemm_kt(
    const _Float16* __restrict__ A, size_t sA, int lda,
    const _Float16* __restrict__ B, size_t sB, int ldb,
    float* __restrict__ out0, _Float16* __restrict__ out1,
    float* __restrict__ out2,
    size_t sO, int ldo,
    const float* __restrict__ bias,
    const float* __restrict__ resid,
    const _Float16* __restrict__ residh,
    const _Float16* __restrict__ cf,
    int K) {
  __shared__ _Float16 lds[3 * 12288];              // 73728 B; reused as bounce
  __shared__ _Float16 clds[(EPI == 6) ? 4096 : 1]; // EPI6: [2 chunks][2048]

  // XCD-bijective swizzle (all grids are multiples of 8 blocks)
  const int gx = gridDim.x, gy = gridDim.y;
  const int nblk = gx * gy * gridDim.z;
  int lin = (blockIdx.z * gy + blockIdx.y) * gx + blockIdx.x;
  lin = (lin & 7) * (nblk >> 3) + (lin >> 3);
  const int b  = lin / (gx * gy);
  const int r2 = lin - b * gx * gy;
  const int m0 = (r2 / gx) * 128;
  const int n0 = (r2 - (r2 / gx) * gx) * 256;

  const int t = threadIdx.x, lane = t & 63, w = t >> 6;
  const int wr = w >> 2;          // wave M-half: rows m0+wr*64..+63
  const int wc = w & 3;           // wave N-quarter: cols n0+wc*64..+63
  const int lr = lane & 15, lq = lane >> 4;

  const _Float16* Ab = A + (size_t)b * sA;
  const _Float16* Bb = B + (size_t)b * sB;

  // staging: thread t stages A seg t, B segs t and t+512 (16B each)
  const int arow = t >> 2;
  const int acol = ((t & 3) ^ ((arow >> 1) & 3)) * 8;  // pre-swizzled source col
  const _Float16* a_src  = Ab + (size_t)(m0 + arow) * lda + acol;
  const _Float16* b_src0 = Bb + (size_t)(n0 + arow) * ldb + acol;
  const _Float16* b_src1 = b_src0 + (size_t)128 * ldb;  // +128 rows: same swizzle class
  const int a_dst  = t * 8;
  const int b_dst0 = 4096 + t * 8;
  const int b_dst1 = 4096 + (t + 512) * 8;

  // ds_read bases (swizzled)
  const int swz  = ((lr >> 1) & 3) << 3;
  const int koff = (lq * 8) ^ swz;                       // swizzled k slot in LDS
  const int a_rd = (wr * 64 + lr) * 32 + koff;           // + f*512
  const int b_rd = 4096 + (wc * 64 + lr) * 32 + koff;    // + j*512

  f32x4 acc[4][4];
#pragma unroll
  for (int f = 0; f < 4; ++f)
#pragma unroll
    for (int j = 0; j < 4; ++j) acc[f][j] = (f32x4){0.f, 0.f, 0.f, 0.f};

  const int NT = K >> 5;

  // prologue: (EPI6) c-table, then stage tiles 0 and 1
  if constexpr (EPI == 6)
    gload16(cf + ((size_t)b * 32 + (m0 >> 6)) * 2048 + t * 8, clds + t * 8);
  gload16(a_src,       lds + a_dst);
  gload16(b_src0,      lds + b_dst0);
  gload16(b_src1,      lds + b_dst1);
  gload16(a_src  + 32, lds + 12288 + a_dst);
  gload16(b_src0 + 32, lds + 12288 + b_dst0);
  gload16(b_src1 + 32, lds + 12288 + b_dst1);

  int buf = 0;
  for (int kt = 0; kt < NT; ++kt) {
    // counted wait: tile kt's loads (and, at kt=0, the c-load) are oldest;
    // leave tile kt+1's 3 in flight
    if (kt + 1 < NT) asm volatile("s_waitcnt vmcnt(3)" ::: "memory");
    else             asm volatile("s_waitcnt vmcnt(0)" ::: "memory");
    __builtin_amdgcn_s_barrier();
    __builtin_amdgcn_sched_barrier(0);  // no ds_read hoists above the barrier

    const _Float16* lb = lds + buf * 12288;
    const int nb = (buf + 2 >= 3) ? buf - 1 : buf + 2;
    _Float16* ln = lds + nb * 12288;

    f16x8 af[4], bf[4], cv;
    if constexpr (EPI == 6)
      // c-table is linear in clds; fragment's global k-group is lq (the
      // store/read XOR cancels) -> index by lq*8, NOT koff
      cv = *(const f16x8*)(clds + wr * 2048 + kt * 32 + lq * 8);
#pragma unroll
    for (int f = 0; f < 4; ++f) {
      af[f] = *(const f16x8*)(lb + a_rd + f * 512);
      if constexpr (EPI == 6) af[f] = af[f] * cv;
    }
#pragma unroll
    for (int j = 0; j < 4; ++j) bf[j] = *(const f16x8*)(lb + b_rd + j * 512);
    if (kt + 2 < NT) {
      const int ko = (kt + 2) * 32;
      gload16(a_src  + ko, ln + a_dst);
      gload16(b_src0 + ko, ln + b_dst0);
      gload16(b_src1 + ko, ln + b_dst1);
    }
    __builtin_amdgcn_s_setprio(1);
#pragma unroll
    for (int f = 0; f < 4; ++f)
#pragma unroll
      for (int j = 0; j < 4; ++j)
        acc[f][j] = __builtin_amdgcn_mfma_f32_16x16x32_f16(af[f], bf[j], acc[f][j], 0, 0, 0);
    __builtin_amdgcn_s_setprio(0);
    __builtin_amdgcn_sched_barrier(0);  // nothing sinks into next tile
    buf = (buf + 1 >= 3) ? 0 : buf + 1;
  }

  // ---- epilogues. D frag: col = lr, row = lq*4 + r ----
  // f16 tiles go through the LDS bounce: wave region w, local
  // row_l = f*16+lq*4+r, stored col = ((j^lq)<<4)+lr  (conflict-free)
  if constexpr (EPI == 0 || EPI == 4 || EPI == 6) {
    __syncthreads();  // all ds_reads of the last tile done; lds is free
    _Float16* breg = lds + w * 4096;
    if constexpr (EPI == 4) {
#pragma unroll
      for (int j = 0; j < 4; ++j) {
        float m = -3.4e38f;
#pragma unroll
        for (int f = 0; f < 4; ++f)
#pragma unroll
          for (int r = 0; r < 4; ++r) m = fmaxf(m, acc[f][j][r]);
#pragma unroll
        for (int d = 16; d <= 32; d <<= 1) m = fmaxf(m, __shfl_xor(m, d, 64));
        float Z = 0.f;
        const int cb = ((j ^ lq) << 4) + lr;
#pragma unroll
        for (int f = 0; f < 4; ++f)
#pragma unroll
          for (int r = 0; r < 4; ++r) {
            const _Float16 eh = (_Float16)__expf(acc[f][j][r] - m);
            breg[(f * 16 + lq * 4 + r) * 64 + cb] = eh;
            Z += (float)eh;
          }
#pragma unroll
        for (int d = 16; d <= 32; d <<= 1) Z += __shfl_xor(Z, d, 64);
        if (lq == 0) {
          const int chunk = (m0 >> 6) + wr;
          const int col = n0 + wc * 64 + j * 16 + lr;
          const size_t sidx = ((size_t)b * 32 + chunk) * 2048 + col;
          out0[sidx] = m;
          out2[sidx] = Z;
        }
      }
    } else {
#pragma unroll
      for (int f = 0; f < 4; ++f)
#pragma unroll
        for (int j = 0; j < 4; ++j) {
          const int cb = ((j ^ lq) << 4) + lr;
#pragma unroll
          for (int r = 0; r < 4; ++r) {
            float v = acc[f][j][r];
            if constexpr (EPI == 0) {
              if (bias) v += bias[n0 + wc * 64 + j * 16 + lr];
            } else {  // EPI == 6
              const int row = m0 + wr * 64 + f * 16 + lq * 4 + r;
              const int col = n0 + wc * 64 + j * 16 + lr;
              v += resid[(size_t)b * sO + (size_t)row * ldo + col];
            }
            breg[(f * 16 + lq * 4 + r) * 64 + cb] = (_Float16)v;
          }
        }
    }
    __syncthreads();
    bounce_flush(lds, out1 + (size_t)b * sO + (size_t)m0 * ldo + n0, ldo, t);
  } else {  // EPI == 3: direct f32 store
#pragma unroll
    for (int f = 0; f < 4; ++f)
#pragma unroll
      for (int j = 0; j < 4; ++j)
#pragma unroll
        for (int r = 0; r < 4; ++r) {
          const int row = m0 + wr * 64 + f * 16 + lq * 4 + r;
          const int col = n0 + wc * 64 + j * 16 + lr;
          const size_t oidx = (size_t)b * sO + (size_t)row * ldo + col;
          const float v = acc[f][j][r];
          out0[oidx] = (float)residh[oidx] + (v > 0.f ? v : 0.f);
        }
  }
}

// ---- all weight converts + bias concat in one dispatch ----
__global__ __launch_bounds__(256) void wconv(
    const float* __restrict__ Wk, const float* __restrict__ Wq,
    const float* __restrict__ W1, const float* __restrict__ W2,
    _Float16* __restrict__ Wkqf, _Float16* __restrict__ W1f,
    _Float16* __restrict__ W2f,
    const float* __restrict__ bk, const float* __restrict__ bq,
    float* __restrict__ bkq) {
  const int by = blockIdx.y;
  const long i = (long)blockIdx.x * 256 + threadIdx.x;
  if (by == 4) {
    if (i < 768) bkq[i] = bk[i];
    else if (i < 1536) bkq[i] = bq[i - 768];
    return;
  }
  const float* in = (by == 0) ? Wk : (by == 1) ? Wq : (by == 2) ? W1 : W2;
  _Float16* outp = (by == 0) ? Wkqf : (by == 1) ? (Wkqf + 589824)
                  : (by == 2) ? W1f : W2f;
  f32x4 v0 = *(const f32x4*)(in + i * 8);
  f32x4 v1 = *(const f32x4*)(in + i * 8 + 4);
  f16x8 o;
  o[0] = (_Float16)v0[0]; o[1] = (_Float16)v0[1]; o[2] = (_Float16)v0[2]; o[3] = (_Float16)v0[3];
  o[4] = (_Float16)v1[0]; o[5] = (_Float16)v1[1]; o[6] = (_Float16)v1[2]; o[7] = (_Float16)v1[3];
  *(f16x8*)(outp + i * 8) = o;
}

// ---- combine 32 chunk partials per column -> c[b][chunk][col] (f16) ----
// c = exp(m_chunk - m) / Z
__global__ __launch_bounds__(256) void col_final(const float* __restrict__ pm,
                                                 const float* __restrict__ pZ,
                                                 _Float16* __restrict__ c) {
  const int b = blockIdx.z;
  const int col = blockIdx.x * 256 + threadIdx.x;
  float mv[32];
  float m = -3.4e38f;
#pragma unroll
  for (int k = 0; k < 32; ++k) {
    mv[k] = pm[((size_t)b * 32 + k) * 2048 + col];
    m = fmaxf(m, mv[k]);
  }
  float Z = 0.f;
#pragma unroll
  for (int k = 0; k < 32; ++k)
    Z += pZ[((size_t)b * 32 + k) * 2048 + col] * __expf(mv[k] - m);
  const float rZ = 1.f / Z;
#pragma unroll
  for (int k = 0; k < 32; ++k)
    c[((size_t)b * 32 + k) * 2048 + col] = (_Float16)(__expf(mv[k] - m) * rZ);
}

// ---- x[b][j][c] f32 -> xf[b][j][c] f16 AND xT[b][c][j] f16, one pass ----
__global__ void xprep(const float* __restrict__ x, _Float16* __restrict__ xf,
                      _Float16* __restrict__ xT) {
  __shared__ float tile[32][33];
  const int b = blockIdx.z;
  const int c0 = blockIdx.x * 32, j0 = blockIdx.y * 32;
  const float* xb = x + (size_t)b * 2048 * 768;
  const int tx = threadIdx.x, ty = threadIdx.y;  // 32 x 8
#pragma unroll
  for (int dy = 0; dy < 32; dy += 8)
    tile[ty + dy][tx] = xb[(size_t)(j0 + ty + dy) * 768 + c0 + tx];
  __syncthreads();
  // straight f16 copy, 4-wide vector stores
  {
    const int u = ty * 32 + tx;          // 0..255
    const int row = u >> 3, c4 = (u & 7) * 4;
    f16x4 o;
#pragma unroll
    for (int q = 0; q < 4; ++q) o[q] = (_Float16)tile[row][c4 + q];
    *(f16x4*)(xf + ((size_t)b * 2048 + j0 + row) * 768 + c0 + c4) = o;
  }
  // transposed f16
  _Float16* xTb = xT + (size_t)b * 768 * 2048;
#pragma unroll
  for (int dy = 0; dy < 32; dy += 8)
    xTb[(size_t)(c0 + ty + dy) * 2048 + j0 + tx] = (_Float16)tile[tx][ty + dy];
}

extern "C" void kernel_launch(void* const* d_in, const int* in_sizes, int n_in,
                              void* d_out, int out_size, void* d_ws, size_t ws_size,
                              hipStream_t stream) {
  const float* x  = (const float*)d_in[0];
  const float* Wk = (const float*)d_in[1];
  const float* bk = (const float*)d_in[2];
  const float* Wq = (const float*)d_in[3];
  const float* bq = (const float*)d_in[4];
  const float* W1 = (const float*)d_in[5];
  const float* W2 = (const float*)d_in[6];
  float* out = (float*)d_out;

  // ---- ws layout (~168 MiB peak) ----
  char* ws = (char*)d_ws;
  size_t off = 0;
  auto alloc = [&](size_t bytes) -> char* {
    char* p = ws + off;
    off += (bytes + 255) & ~(size_t)255;
    return p;
  };
  _Float16* xf = (_Float16*)alloc(25165824);   // x f16 row-major
  _Float16* kq = (_Float16*)alloc(50331648);   // [16384][1536] k|q; reused p_f16+c+h
  _Float16* Wf = (_Float16*)alloc(4718592);    // Wkq, W1, W2 f16
  _Float16* E  = (_Float16*)alloc(67108864);   // E' = exp(S - m_chunk) f16
  _Float16* xT = (_Float16*)alloc(25165824);   // x^T f16 [b][c][j]
  float*    pm = (float*)alloc(2097152);       // [8][32][2048] partial max
  float*    pZ = (float*)alloc(2097152);       // [8][32][2048] partial sumexp
  float*    bkq  = (float*)alloc(6144);

  _Float16* Wkqf = Wf;
  _Float16* W1f  = Wf + 2 * 589824;
  _Float16* W2f  = Wf + 3 * 589824;
  _Float16* pf16 = kq;                 // alias after E pass consumed kq
  _Float16* cT   = kq + 12582912;      // c table (1MiB) in dead kq space
  _Float16* hf16 = kq + 12582912;      // FFN1 out overwrites cT AFTER PV (stream order)

  const size_t sKQ = (size_t)2048 * 1536;
  const size_t sS  = (size_t)2048 * 2048;
  const size_t sKV = (size_t)2048 * 768;

  // 1. x prep (f16 + transpose, one pass) + all weight converts (one dispatch)
  xprep<<<dim3(24, 64, 8), dim3(32, 8), 0, stream>>>(x, xf, xT);
  wconv<<<dim3(288, 5), 256, 0, stream>>>(Wk, Wq, W1, W2, Wkqf, W1f, W2f,
                                          bk, bq, bkq);

  // 2. merged projection: kq = x * Wkq^T + bkq  (M=16384, N=1536, K=768)
  gemm_kt<0><<<dim3(6, 128, 1), 512, 0, stream>>>(xf, 0, 768, Wkqf, 0, 768,
                                                  nullptr, kq, nullptr, 0, 1536,
                                                  bkq, nullptr, nullptr, nullptr, 768);

  // 3. E pass: S = k q^T; E' = exp(S - m_chunk) f16 + (m,Z) partials
  gemm_kt<4><<<dim3(8, 16, 8), 512, 0, stream>>>(kq, sKQ, 1536, kq + 768, sKQ, 1536,
                                                 pm, E, pZ, sS, 2048,
                                                 nullptr, nullptr, nullptr, nullptr, 768);
  col_final<<<dim3(8, 1, 8), 256, 0, stream>>>(pm, pZ, cT);

  // 4. fused PV: p = x + (E' .* c) x  (M=2048, N=768, K=2048), f16 out only
  gemm_kt<6><<<dim3(3, 16, 8), 512, 0, stream>>>(E, sS, 2048, xT, sKV, 2048,
                                                 nullptr, pf16, nullptr, sKV, 768,
                                                 nullptr, x, nullptr, cT, 2048);

  // 5. FFN1: h = p * W1^T (f16 out; overwrites cT — PV done)
  gemm_kt<0><<<dim3(3, 128, 1), 512, 0, stream>>>(pf16, 0, 768, W1f, 0, 768,
                                                  nullptr, hf16, nullptr, 0, 768,
                                                  nullptr, nullptr, nullptr, nullptr, 768);

  // 6. FFN2 + residual + relu: out = (f32)p_f16 + relu(h * W2^T)
  gemm_kt<3><<<dim3(3, 128, 1), 512, 0, stream>>>(hf16, 0, 768, W2f, 0, 768,
                                                  out, nullptr, nullptr, 0, 768,
                                                  nullptr, nullptr, pf16, nullptr, 768);
}